// Round 4
// baseline (13389.911 us; speedup 1.0000x reference)
//
#include <hip/hip_runtime.h>

#define B   32
#define T   64
#define D   512
#define H   512
#define H2  1024
#define G4  4096
#define V   2048
#define DEC_IN 2560

__device__ __forceinline__ float sigm(float x) { return 1.f / (1.f + expf(-x)); }

__device__ __forceinline__ unsigned fenc(float f) {
  unsigned u = __float_as_uint(f);
  return (u & 0x80000000u) ? ~u : (u | 0x80000000u);
}

// ---- two-level tree grid barrier ----
// slot layout (u32): leaf[16] at g*16, root at 256, flag[16] at 272+g*16; stride 544.
#define SLOT_U32 544
__device__ __forceinline__ void fbar(unsigned* slot, int leafId, unsigned leafTarget) {
  __syncthreads();
  if (threadIdx.x == 0) {
    unsigned o = __hip_atomic_fetch_add(slot + leafId*16, 1u, __ATOMIC_ACQ_REL, __HIP_MEMORY_SCOPE_AGENT);
    if (o == leafTarget - 1u) {
      unsigned r = __hip_atomic_fetch_add(slot + 256, 1u, __ATOMIC_ACQ_REL, __HIP_MEMORY_SCOPE_AGENT);
      if (r == 15u) {
        #pragma unroll
        for (int g = 0; g < 16; ++g)
          __hip_atomic_store(slot + 272 + g*16, 1u, __ATOMIC_RELEASE, __HIP_MEMORY_SCOPE_AGENT);
      }
    }
    unsigned* f = slot + 272 + leafId*16;
    while (!__hip_atomic_load(f, __ATOMIC_RELAXED, __HIP_MEMORY_SCOPE_AGENT))
      __builtin_amdgcn_s_sleep(2);
    (void)__hip_atomic_load(f, __ATOMIC_ACQUIRE, __HIP_MEMORY_SCOPE_AGENT);
  }
  __syncthreads();
}

// ---------------- generic fp32 GEMM:  C[m,n] = sum_k A[m,k]*W[n,k] + bias0[n] + bias1[n]
__global__ __launch_bounds__(256) void gemm_nt(
    const float* __restrict__ A, int lda,
    const float* __restrict__ W, int ldw,
    float* __restrict__ C, int ldc,
    const float* __restrict__ bias0, const float* __restrict__ bias1,
    int K)
{
  __shared__ float As[16][132];
  __shared__ float Ws[16][68];
  const int tid = threadIdx.x;
  const int nb = blockIdx.x * 64;
  const int mb = blockIdx.y * 128;
  const int tx = tid & 15;
  const int ty = tid >> 4;
  float acc[8][4] = {};

  const int am = tid >> 1, ak = (tid & 1) * 8;
  const int wn = tid >> 2, wk = (tid & 3) * 4;
  const float* aptr = A + (size_t)(mb + am) * lda + ak;
  const float* wptr = W + (size_t)(nb + wn) * ldw + wk;

  for (int k0 = 0; k0 < K; k0 += 16) {
    float4 u = *(const float4*)(aptr + k0);
    float4 v = *(const float4*)(aptr + k0 + 4);
    float4 w = *(const float4*)(wptr + k0);
    As[ak+0][am] = u.x; As[ak+1][am] = u.y; As[ak+2][am] = u.z; As[ak+3][am] = u.w;
    As[ak+4][am] = v.x; As[ak+5][am] = v.y; As[ak+6][am] = v.z; As[ak+7][am] = v.w;
    Ws[wk+0][wn] = w.x; Ws[wk+1][wn] = w.y; Ws[wk+2][wn] = w.z; Ws[wk+3][wn] = w.w;
    __syncthreads();
    #pragma unroll
    for (int k = 0; k < 16; ++k) {
      float4 a0 = *(const float4*)&As[k][ty*8];
      float4 a1 = *(const float4*)&As[k][ty*8+4];
      float4 wv = *(const float4*)&Ws[k][tx*4];
      float av[8] = {a0.x,a0.y,a0.z,a0.w,a1.x,a1.y,a1.z,a1.w};
      #pragma unroll
      for (int i = 0; i < 8; ++i) {
        acc[i][0] += av[i]*wv.x; acc[i][1] += av[i]*wv.y;
        acc[i][2] += av[i]*wv.z; acc[i][3] += av[i]*wv.w;
      }
    }
    __syncthreads();
  }
  float b4[4];
  #pragma unroll
  for (int j = 0; j < 4; ++j) {
    float bv = 0.f;
    if (bias0) bv += bias0[nb + tx*4 + j];
    if (bias1) bv += bias1[nb + tx*4 + j];
    b4[j] = bv;
  }
  #pragma unroll
  for (int i = 0; i < 8; ++i) {
    float4 o;
    o.x = acc[i][0] + b4[0]; o.y = acc[i][1] + b4[1];
    o.z = acc[i][2] + b4[2]; o.w = acc[i][3] + b4[3];
    *(float4*)&C[(size_t)(mb + ty*8 + i) * ldc + nb + tx*4] = o;
  }
}

// ---------------- attention helper: block handles batch row b; writes ctx transposed ----
__device__ void attend_t(int b, const float* __restrict__ hvec, float* __restrict__ ctxdst,
                         const float* __restrict__ outbuf, const float* __restrict__ projo,
                         const int* __restrict__ mask, float* scratch, int tid)
{
  float* scp = scratch;        // 256
  float* scv = scratch + 256;  // 64
  const int tq = tid >> 2, dq = tid & 3;
  const float4* hv = (const float4*)(hvec + dq*256);
  const float4* pv = (const float4*)(projo + (size_t)(b*T + tq)*H2 + dq*256);
  float p = 0.f;
  #pragma unroll 8
  for (int k4 = 0; k4 < 64; ++k4) {
    float4 a = hv[k4], q = pv[k4];
    p += a.x*q.x + a.y*q.y + a.z*q.z + a.w*q.w;
  }
  scp[tid] = p;
  __syncthreads();
  if (tid < 64) {
    float v = scp[tid*4] + scp[tid*4+1] + scp[tid*4+2] + scp[tid*4+3];
    float mx = v;
    #pragma unroll
    for (int d = 32; d; d >>= 1) mx = fmaxf(mx, __shfl_xor(mx, d, 64));
    float e = expf(v - mx);
    float sm = e;
    #pragma unroll
    for (int d = 32; d; d >>= 1) sm += __shfl_xor(sm, d, 64);
    scv[tid] = e * (1.f / sm) * (float)mask[b*T + tid];
  }
  __syncthreads();
  float a0 = 0, a1 = 0, a2 = 0, a3 = 0;
  #pragma unroll 16
  for (int tt = 0; tt < 64; ++tt) {
    float pp = scv[tt];
    float4 o4 = *(const float4*)(outbuf + (size_t)(b*T + tt)*H2 + tid*4);
    a0 += pp*o4.x; a1 += pp*o4.y; a2 += pp*o4.z; a3 += pp*o4.w;
  }
  int k0 = tid*4;
  ctxdst[(k0+0)*32 + b] = a0;
  ctxdst[(k0+1)*32 + b] = a1;
  ctxdst[(k0+2)*32 + b] = a2;
  ctxdst[(k0+3)*32 + b] = a3;
}

// ---- decoder slice staging helpers: state = [h(1024 rows); ctx(1024 rows)] x 32b,
// slices of 128 rows; LDS S1 row stride 34.
__device__ __forceinline__ void load_slice(float4 r[4], int sl, const float* b0, const float* b1, int tid) {
  const float* s = (sl < 8) ? (b0 + sl*4096) : (b1 + (sl-8)*4096);
  #pragma unroll
  for (int q = 0; q < 4; ++q) r[q] = *(const float4*)(s + q*1024 + tid*4);
}
__device__ __forceinline__ void store_slice(float* S1, const float4 r[4], int tid) {
  const int row0 = tid >> 3, c = 4*(tid & 7);
  #pragma unroll
  for (int q = 0; q < 4; ++q)
    *(float4*)&S1[(q*32 + row0)*34 + c] = r[q];
}
__device__ __forceinline__ void comp_gates(const float* S1, const float* Wg, int sl,
                                           int jl0, int jl1, int kk,
                                           float a0[32], float a1[32])
{
  #pragma unroll
  for (int i = 0; i < 4; ++i) {
    float w0 = Wg[jl0*2052 + sl*128 + i*32 + kk];
    float w1 = Wg[jl1*2052 + sl*128 + i*32 + kk];
    const float* sp = S1 + (i*32 + kk)*34;
    #pragma unroll
    for (int q = 0; q < 8; ++q) {
      float4 s4 = *(const float4*)(sp + q*4);
      a0[q*4+0] += w0*s4.x; a0[q*4+1] += w0*s4.y; a0[q*4+2] += w0*s4.z; a0[q*4+3] += w0*s4.w;
      a1[q*4+0] += w1*s4.x; a1[q*4+1] += w1*s4.y; a1[q*4+2] += w1*s4.z; a1[q*4+3] += w1*s4.w;
    }
  }
}
__device__ __forceinline__ void comp_scores(const float* S1, const float* ws0, const float* ws1,
                                            int sl, int kq, float a0[32], float a1[32])
{
  #pragma unroll
  for (int i = 0; i < 2; ++i) {
    float w0 = ws0[sl*2+i], w1 = ws1[sl*2+i];
    const float* sp = S1 + (i*64 + kq)*34;
    #pragma unroll
    for (int q = 0; q < 8; ++q) {
      float4 s4 = *(const float4*)(sp + q*4);
      a0[q*4+0] += w0*s4.x; a0[q*4+1] += w0*s4.y; a0[q*4+2] += w0*s4.z; a0[q*4+3] += w0*s4.w;
      a1[q*4+0] += w1*s4.x; a1[q*4+1] += w1*s4.y; a1[q*4+2] += w1*s4.z; a1[q*4+3] += w1*s4.w;
    }
  }
}

// ---------------- persistent encoder: weights in registers (32 floats/thread) ----------
__global__ __launch_bounds__(256, 1) void encoder_persistent(
    const float* __restrict__ xg_f, const float* __restrict__ xg_b,
    const float* __restrict__ Whh_f, const float* __restrict__ Whh_b,
    const int* __restrict__ mask,
    float* __restrict__ hencT,    // [dir][2][512][32]
    float* __restrict__ outbuf,
    unsigned* __restrict__ ebar)
{
  __shared__ float S_lds[2][128*36];
  __shared__ float pacc[2048];
  __shared__ float g_lds[512];
  const int blk = blockIdx.x, tid = threadIdx.x;
  const int lane = tid & 63, wv = tid >> 6;
  const int dir = blk >> 7, nd = blk & 127;
  const int hibase = nd * 4;
  const int jj = tid & 7, kk = tid >> 3;
  const float* xg  = dir ? xg_b : xg_f;
  const float* Whh = dir ? Whh_b : Whh_f;
  float* hbase = hencT + dir * 32768;
  unsigned* bc = ebar + dir * 64 * SLOT_U32;

  float wge[2][16];
  #pragma unroll
  for (int p = 0; p < 2; ++p) {
    int jl = jj*2 + p;
    int j = (jl>>2)*512 + hibase + (jl&3);
    #pragma unroll
    for (int sc = 0; sc < 4; ++sc)
      #pragma unroll
      for (int i = 0; i < 4; ++i)
        wge[p][sc*4+i] = Whh[(size_t)j*512 + sc*128 + i*32 + kk];
  }
  float c_reg = 0.f;
  const int kr = tid >> 1, bh = (tid & 1) * 16;

  for (int tt = 0; tt < 64; ++tt) {
    const int t = dir ? (63 - tt) : tt;
    const float* hc = hbase + (tt & 1) * 16384;
    float* hn = hbase + ((tt + 1) & 1) * 16384;

    float a0[32], a1[32];
    #pragma unroll
    for (int q = 0; q < 32; ++q) { a0[q] = 0.f; a1[q] = 0.f; }

    float4 rr0, rr1, rr2, rr3;
    {
      const float4* p = (const float4*)(hc + kr*32 + bh);
      rr0 = p[0]; rr1 = p[1]; rr2 = p[2]; rr3 = p[3];
      float* d = &S_lds[0][kr*36 + bh];
      *(float4*)d = rr0; *(float4*)(d+4) = rr1; *(float4*)(d+8) = rr2; *(float4*)(d+12) = rr3;
    }
    __syncthreads();
    #pragma unroll
    for (int sc = 0; sc < 4; ++sc) {
      if (sc < 3) {
        const float4* p = (const float4*)(hc + (sc+1)*4096 + kr*32 + bh);
        rr0 = p[0]; rr1 = p[1]; rr2 = p[2]; rr3 = p[3];
      }
      const float* Sb = &S_lds[sc & 1][0];
      #pragma unroll
      for (int i = 0; i < 4; ++i) {
        const float* sp = Sb + (i*32 + kk)*36;
        float w0 = wge[0][sc*4+i], w1 = wge[1][sc*4+i];
        #pragma unroll
        for (int q = 0; q < 8; ++q) {
          float4 s4 = *(const float4*)(sp + q*4);
          a0[q*4+0] += w0*s4.x; a0[q*4+1] += w0*s4.y; a0[q*4+2] += w0*s4.z; a0[q*4+3] += w0*s4.w;
          a1[q*4+0] += w1*s4.x; a1[q*4+1] += w1*s4.y; a1[q*4+2] += w1*s4.z; a1[q*4+3] += w1*s4.w;
        }
      }
      if (sc < 3) {
        float* d = &S_lds[(sc+1) & 1][kr*36 + bh];
        *(float4*)d = rr0; *(float4*)(d+4) = rr1; *(float4*)(d+8) = rr2; *(float4*)(d+12) = rr3;
      }
      __syncthreads();
    }
    #pragma unroll
    for (int dd = 8; dd <= 32; dd <<= 1) {
      #pragma unroll
      for (int q = 0; q < 32; ++q) {
        a0[q] += __shfl_down(a0[q], dd, 64);
        a1[q] += __shfl_down(a1[q], dd, 64);
      }
    }
    if (lane < 8) {
      float* pw = &pacc[wv*512 + lane*64];
      #pragma unroll
      for (int q = 0; q < 32; ++q) { pw[q] = a0[q]; pw[32+q] = a1[q]; }
    }
    __syncthreads();
    #pragma unroll
    for (int r = 0; r < 2; ++r) {
      int o = tid + r*256;
      int jl = o >> 5, b = o & 31;
      int off = (jl>>1)*64 + (jl&1)*32 + b;
      float v = pacc[off] + pacc[512+off] + pacc[1024+off] + pacc[1536+off];
      v += xg[(size_t)(b*T + t)*2048 + (jl>>2)*512 + hibase + (jl&3)];
      g_lds[jl*32 + b] = v;
    }
    __syncthreads();
    if (tid < 128) {
      int hil = tid >> 5, b = tid & 31;
      float gi = g_lds[(0*4+hil)*32 + b];
      float gf = g_lds[(1*4+hil)*32 + b];
      float gg = g_lds[(2*4+hil)*32 + b];
      float go = g_lds[(3*4+hil)*32 + b];
      c_reg = sigm(gf)*c_reg + sigm(gi)*tanhf(gg);
      float h = sigm(go)*tanhf(c_reg);
      int hi = hibase + hil;
      hn[hi*32 + b] = h;
      outbuf[(size_t)(b*T + t)*H2 + dir*512 + hi] = h * (float)mask[b*T + t];
    }
    fbar(bc + tt*SLOT_U32, nd & 15, 8);
  }
}

// ---------------- persistent decoder: gates weights in LDS, scores weights in regs ------
// Dynamic LDS (floats): Wg 16x2052=32832 | S1 128x34=4352 | pacc 2048 | g_lds 512
// total 39744 floats = 158976 B
__global__ __launch_bounds__(256, 1) void decoder_persistent(
    const float* __restrict__ basep, const float* __restrict__ tagp,
    const float* __restrict__ dWhh,  const float* __restrict__ dWih,
    const float* __restrict__ Wout,  const float* __restrict__ bout,
    const float* __restrict__ projo, const float* __restrict__ outbuf,
    const int* __restrict__ mask,
    float* __restrict__ hT,          // [2][1024][32]
    float* __restrict__ ctxT,        // [2][1024][32]
    float* __restrict__ hrow,        // [32][1024]
    unsigned long long* __restrict__ argslot,
    unsigned* __restrict__ dbar,
    float* __restrict__ out)
{
  extern __shared__ float dyn[];
  float* Wg    = dyn;           // 32832
  float* S1    = dyn + 32832;   // 4352
  float* pacc  = dyn + 37184;   // 2048
  float* g_lds = dyn + 39232;   // 512

  const int blk = blockIdx.x, tid = threadIdx.x;
  const int lane = tid & 63, wv = tid >> 6;
  const int hibase = blk * 4;
  const int jj = tid & 7, kk = tid >> 3;     // gates mapping
  const int jl0 = jj*2, jl1 = jj*2 + 1;
  const int vv = tid & 3, kq = tid >> 2;     // scores mapping
  const int vbase = blk * 8;

  // ---- preload gates weights into LDS (once) ----
  for (int jl = 0; jl < 16; ++jl) {
    int j = (jl>>2)*1024 + hibase + (jl&3);
    #pragma unroll
    for (int r = 0; r < 2; ++r) {
      int c = tid*4 + r*1024;
      float4 w;
      if (c < 1024) w = *(const float4*)(dWhh + (size_t)j*1024 + c);
      else          w = *(const float4*)(dWih + (size_t)j*2560 + 512 + (c - 1024));
      *(float4*)&Wg[jl*2052 + c] = w;
    }
  }
  // ---- scores weights in registers (64 floats/thread) ----
  float ws0[32], ws1[32];
  {
    int v0 = vbase + vv*2;
    #pragma unroll
    for (int s2 = 0; s2 < 32; ++s2) {
      ws0[s2] = Wout[(size_t)(v0+0)*2048 + s2*64 + kq];
      ws1[s2] = Wout[(size_t)(v0+1)*2048 + s2*64 + kq];
    }
  }

  float c_reg = 0.f;
  int bslot = 0;

  // ---- prologue: context0 = attend(last_output) ----
  if (blk < 32) {
    int b = blk;
    int len = -1;
    for (int i = 0; i < T; ++i) len += mask[b*T + i];
    attend_t(b, outbuf + (size_t)(b*T + len)*H2, ctxT, outbuf, projo, mask, pacc, tid);
  }
  fbar(dbar + (bslot++)*SLOT_U32, blk & 15, 16);

  for (int t = 0; t < T; ++t) {
    const int cur = t & 1, nxt = cur ^ 1;
    const float* hTc  = hT + cur*32768;
    float*       hTn  = hT + nxt*32768;
    const float* ctxc = ctxT + cur*32768;
    float*       ctxn = ctxT + nxt*32768;

    // prefetch per-thread external gate contributions (base + tag embed proj)
    const int b_own = tid & 31;
    const int jlA = tid >> 5, jlB = jlA + 8;
    const int jA = (jlA>>2)*1024 + hibase + (jlA&3);
    const int jB = (jlB>>2)*1024 + hibase + (jlB&3);
    float extA = basep[(size_t)(b_own*T + t)*G4 + jA];
    float extB = basep[(size_t)(b_own*T + t)*G4 + jB];
    if (t > 0) {
      unsigned tg = ~(unsigned)argslot[((t+2)%3)*32 + b_own];
      extA += tagp[(size_t)tg*G4 + jA];
      extB += tagp[(size_t)tg*G4 + jB];
    }

    // ===== phase 1: gates (K=2048: h | ctx), weights from LDS =====
    float a0[32], a1[32];
    #pragma unroll
    for (int q = 0; q < 32; ++q) { a0[q] = 0.f; a1[q] = 0.f; }
    {
      float4 rA[4], rB[4];
      load_slice(rA, 0, hTc, ctxc, tid);
      store_slice(S1, rA, tid);
      load_slice(rA, 1, hTc, ctxc, tid);
      __syncthreads();
      for (int sp2 = 0; sp2 < 8; ++sp2) {
        int sl = sp2*2;
        if (sl + 2 < 16) load_slice(rB, sl+2, hTc, ctxc, tid);
        comp_gates(S1, Wg, sl, jl0, jl1, kk, a0, a1);
        __syncthreads();
        store_slice(S1, rA, tid);          // slice sl+1
        __syncthreads();
        if (sl + 3 < 16) load_slice(rA, sl+3, hTc, ctxc, tid);
        comp_gates(S1, Wg, sl+1, jl0, jl1, kk, a0, a1);
        __syncthreads();
        if (sl + 2 < 16) store_slice(S1, rB, tid);   // slice sl+2
        __syncthreads();
      }
    }
    #pragma unroll
    for (int dd = 8; dd <= 32; dd <<= 1) {
      #pragma unroll
      for (int q = 0; q < 32; ++q) {
        a0[q] += __shfl_down(a0[q], dd, 64);
        a1[q] += __shfl_down(a1[q], dd, 64);
      }
    }
    if (lane < 8) {
      float* pw = &pacc[wv*512 + lane*64];
      #pragma unroll
      for (int q = 0; q < 32; ++q) { pw[q] = a0[q]; pw[32+q] = a1[q]; }
    }
    __syncthreads();
    #pragma unroll
    for (int r = 0; r < 2; ++r) {
      int o = tid + r*256;
      int jl = o >> 5, b = o & 31;
      int off = (jl>>1)*64 + (jl&1)*32 + b;
      float vsum = pacc[off] + pacc[512+off] + pacc[1024+off] + pacc[1536+off];
      vsum += (r == 0) ? extA : extB;
      g_lds[jl*32 + b] = vsum;
    }
    __syncthreads();
    if (tid < 128) {
      int hil = tid >> 5, b = tid & 31;
      float gi = g_lds[(0*4+hil)*32 + b];
      float gf = g_lds[(1*4+hil)*32 + b];
      float gg = g_lds[(2*4+hil)*32 + b];
      float go = g_lds[(3*4+hil)*32 + b];
      c_reg = sigm(gf)*c_reg + sigm(gi)*tanhf(gg);
      float h = sigm(go)*tanhf(c_reg);
      int hi = hibase + hil;
      hTn[hi*32 + b] = h;
      hrow[b*1024 + hi] = h;
    }
    fbar(dbar + (bslot++)*SLOT_U32, blk & 15, 16);

    // ===== phase 2: scores (K=2048: h_new | ctx_old), weights in regs =====
    #pragma unroll
    for (int q = 0; q < 32; ++q) { a0[q] = 0.f; a1[q] = 0.f; }
    {
      float4 rA[4], rB[4];
      load_slice(rA, 0, hTn, ctxc, tid);
      store_slice(S1, rA, tid);
      load_slice(rA, 1, hTn, ctxc, tid);
      __syncthreads();
      #pragma unroll
      for (int sp2 = 0; sp2 < 8; ++sp2) {
        const int sl = sp2*2;
        if (sl + 2 < 16) load_slice(rB, sl+2, hTn, ctxc, tid);
        comp_scores(S1, ws0, ws1, sl, kq, a0, a1);
        __syncthreads();
        store_slice(S1, rA, tid);
        __syncthreads();
        if (sl + 3 < 16) load_slice(rA, sl+3, hTn, ctxc, tid);
        comp_scores(S1, ws0, ws1, sl+1, kq, a0, a1);
        __syncthreads();
        if (sl + 2 < 16) store_slice(S1, rB, tid);
        __syncthreads();
      }
    }
    #pragma unroll
    for (int dd = 4; dd <= 32; dd <<= 1) {
      #pragma unroll
      for (int q = 0; q < 32; ++q) {
        a0[q] += __shfl_down(a0[q], dd, 64);
        a1[q] += __shfl_down(a1[q], dd, 64);
      }
    }
    if (lane < 4) {
      float* pw = &pacc[wv*256 + lane*64];
      #pragma unroll
      for (int q = 0; q < 32; ++q) { pw[q] = a0[q]; pw[32+q] = a1[q]; }
    }
    __syncthreads();
    {
      int vl = tid & 7, b = tid >> 3;
      int off = (vl>>1)*64 + (vl&1)*32 + b;
      float s = pacc[off] + pacc[256+off] + pacc[512+off] + pacc[768+off];
      s += bout[vbase + vl];
      out[(size_t)(b*T + t)*V + vbase + vl] = s;
      g_lds[vl*32 + b] = s;
    }
    __syncthreads();
    if (tid < 32) {
      int b = tid;
      float best = g_lds[b]; int bi = 0;
      #pragma unroll
      for (int vl = 1; vl < 8; ++vl) {
        float s = g_lds[vl*32 + b];
        if (s > best) { best = s; bi = vl; }
      }
      unsigned long long e = ((unsigned long long)fenc(best) << 32)
                           | (unsigned long long)(unsigned)(~(unsigned)(vbase + bi));
      atomicMax(&argslot[(t%3)*32 + b], e);
    } else if (blk == 0 && tid >= 32 && tid < 64) {
      argslot[((t+1)%3)*32 + (tid - 32)] = 0ull;
    }
    if (blk < 32) {
      __syncthreads();
      attend_t(blk, hrow + blk*1024, ctxn, outbuf, projo, mask, pacc, tid);
    }
    fbar(dbar + (bslot++)*SLOT_U32, blk & 15, 16);
  }
}

// ---------------- host launch ----------------
extern "C" void kernel_launch(void* const* d_in, const int* in_sizes, int n_in,
                              void* d_out, int out_size, void* d_ws, size_t ws_size,
                              hipStream_t stream)
{
  (void)in_sizes; (void)n_in; (void)out_size; (void)ws_size;
  const float* emb    = (const float*)d_in[0];
  const int*   mask   = (const int*)d_in[1];
  const float* Wih_f  = (const float*)d_in[2];
  const float* Whh_f  = (const float*)d_in[3];
  const float* bih_f  = (const float*)d_in[4];
  const float* bhh_f  = (const float*)d_in[5];
  const float* Wih_b  = (const float*)d_in[6];
  const float* Whh_b  = (const float*)d_in[7];
  const float* bih_b  = (const float*)d_in[8];
  const float* bhh_b  = (const float*)d_in[9];
  const float* attnW  = (const float*)d_in[10];
  const float* tagemb = (const float*)d_in[12];
  const float* dWih   = (const float*)d_in[13];
  const float* dWhh   = (const float*)d_in[14];
  const float* dbih   = (const float*)d_in[15];
  const float* dbhh   = (const float*)d_in[16];
  const float* Wout   = (const float*)d_in[17];
  const float* bout   = (const float*)d_in[18];
  float* out = (float*)d_out;

  float* ws = (float*)d_ws;
  float* xg_f   = ws + 0;          // 4194304
  float* xg_b   = ws + 4194304;    // 4194304
  float* outbuf = ws + 8388608;    // 2097152
  float* projo  = ws + 10485760;   // 2097152
  float* basep  = ws + 12582912;   // 8388608
  float* tagp   = ws + 20971520;   // 8388608
  float* hT     = ws + 29360128;   // 65536  [2][1024][32]
  float* ctxT   = ws + 29425664;   // 65536  [2][1024][32]
  float* hrow   = ws + 29491200;   // 32768
  float* hencT  = ws + 29523968;   // 65536  [2][2][512][32]
  unsigned long long* argslot = (unsigned long long*)(ws + 29589504);  // 96 u64 (192 floats)
  unsigned* dbar = (unsigned*)(ws + 29589696);   // 129*544 = 70176 u32
  unsigned* ebar = (unsigned*)(ws + 29659872);   // 128*544 = 69632 u32
  // end: 29729504 floats

  // allow 158976 B dynamic LDS for the decoder
  (void)hipFuncSetAttribute((const void*)decoder_persistent,
                            hipFuncAttributeMaxDynamicSharedMemorySize, 158976);

  // zero all persistent-kernel state every call (graph-replay deterministic)
  hipMemsetAsync((void*)(ws + 29360128), 0, (size_t)(29729504 - 29360128) * sizeof(float), stream);

  // xg = emb @ Wih^T + bih + bhh   (M=2048, N=2048, K=512)
  gemm_nt<<<dim3(32, 16), 256, 0, stream>>>(emb, 512, Wih_f, 512, xg_f, 2048, bih_f, bhh_f, 512);
  gemm_nt<<<dim3(32, 16), 256, 0, stream>>>(emb, 512, Wih_b, 512, xg_b, 2048, bih_b, bhh_b, 512);
  // tagp = tag_embed @ dec_Wih[:, :512]^T   (M=2048, N=4096, K=512)
  gemm_nt<<<dim3(64, 16), 256, 0, stream>>>(tagemb, 512, dWih, DEC_IN, tagp, G4, nullptr, nullptr, 512);
  // encoder scan (persistent, register-resident Whh)
  encoder_persistent<<<256, 256, 0, stream>>>(xg_f, xg_b, Whh_f, Whh_b, mask, hencT, outbuf, ebar);
  // projo[bt,d] = sum_e attn_W[d,e]*output[bt,e]   (M=2048, N=1024, K=1024)
  gemm_nt<<<dim3(16, 16), 256, 0, stream>>>(outbuf, H2, attnW, H2, projo, H2, nullptr, nullptr, H2);
  // basep = aligned @ dec_Wih[:,1536:]^T + dbih + dbhh   (M=2048, N=4096, K=1024)
  gemm_nt<<<dim3(64, 16), 256, 0, stream>>>(outbuf, H2, dWih + 1536, DEC_IN, basep, G4, dbih, dbhh, H2);
  // persistent decoder
  decoder_persistent<<<256, 256, 158976, stream>>>(basep, tagp, dWhh, dWih, Wout, bout,
                                                   projo, outbuf, mask, hT, ctxT, hrow,
                                                   argslot, dbar, out);
}

// Round 6
// 6484.411 us; speedup vs baseline: 2.0649x; 2.0649x over previous
//
#include <hip/hip_runtime.h>

#define B   32
#define T   64
#define D   512
#define H   512
#define H2  1024
#define G4  4096
#define V   2048
#define DEC_IN 2560

__device__ __forceinline__ float sigm(float x) { return 1.f / (1.f + expf(-x)); }

__device__ __forceinline__ unsigned fenc(float f) {
  unsigned u = __float_as_uint(f);
  return (u & 0x80000000u) ? ~u : (u | 0x80000000u);
}

// ---- store-based parallel grid barrier (no RMW serialization) ----
// slots: u32[nblk] (fresh per barrier), flag: u32 (fresh per barrier, own line).
// Arrivals are parallel release-stores; block myid==0 collects; one flag fan-out.
__device__ __forceinline__ void pbar(unsigned* slots, unsigned* flag, int myid, int nblk) {
  __syncthreads();
  if (threadIdx.x == 0)
    __hip_atomic_store(slots + myid, 1u, __ATOMIC_RELEASE, __HIP_MEMORY_SCOPE_AGENT);
  if (myid == 0) {
    for (int s = threadIdx.x; s < nblk; s += 256) {
      while (!__hip_atomic_load(slots + s, __ATOMIC_RELAXED, __HIP_MEMORY_SCOPE_AGENT))
        __builtin_amdgcn_s_sleep(1);
    }
    __syncthreads();
    if (threadIdx.x == 0)
      __hip_atomic_store(flag, 1u, __ATOMIC_RELEASE, __HIP_MEMORY_SCOPE_AGENT);
  }
  if (threadIdx.x == 0) {
    while (!__hip_atomic_load(flag, __ATOMIC_RELAXED, __HIP_MEMORY_SCOPE_AGENT))
      __builtin_amdgcn_s_sleep(1);
    (void)__hip_atomic_load(flag, __ATOMIC_ACQUIRE, __HIP_MEMORY_SCOPE_AGENT);
  }
  __syncthreads();
}

// ---------------- generic fp32 GEMM:  C[m,n] = sum_k A[m,k]*W[n,k] + bias0[n] + bias1[n]
__global__ __launch_bounds__(256) void gemm_nt(
    const float* __restrict__ A, int lda,
    const float* __restrict__ W, int ldw,
    float* __restrict__ C, int ldc,
    const float* __restrict__ bias0, const float* __restrict__ bias1,
    int K)
{
  __shared__ float As[16][132];
  __shared__ float Ws[16][68];
  const int tid = threadIdx.x;
  const int nb = blockIdx.x * 64;
  const int mb = blockIdx.y * 128;
  const int tx = tid & 15;
  const int ty = tid >> 4;
  float acc[8][4] = {};

  const int am = tid >> 1, ak = (tid & 1) * 8;
  const int wn = tid >> 2, wk = (tid & 3) * 4;
  const float* aptr = A + (size_t)(mb + am) * lda + ak;
  const float* wptr = W + (size_t)(nb + wn) * ldw + wk;

  for (int k0 = 0; k0 < K; k0 += 16) {
    float4 u = *(const float4*)(aptr + k0);
    float4 v = *(const float4*)(aptr + k0 + 4);
    float4 w = *(const float4*)(wptr + k0);
    As[ak+0][am] = u.x; As[ak+1][am] = u.y; As[ak+2][am] = u.z; As[ak+3][am] = u.w;
    As[ak+4][am] = v.x; As[ak+5][am] = v.y; As[ak+6][am] = v.z; As[ak+7][am] = v.w;
    Ws[wk+0][wn] = w.x; Ws[wk+1][wn] = w.y; Ws[wk+2][wn] = w.z; Ws[wk+3][wn] = w.w;
    __syncthreads();
    #pragma unroll
    for (int k = 0; k < 16; ++k) {
      float4 a0 = *(const float4*)&As[k][ty*8];
      float4 a1 = *(const float4*)&As[k][ty*8+4];
      float4 wv = *(const float4*)&Ws[k][tx*4];
      float av[8] = {a0.x,a0.y,a0.z,a0.w,a1.x,a1.y,a1.z,a1.w};
      #pragma unroll
      for (int i = 0; i < 8; ++i) {
        acc[i][0] += av[i]*wv.x; acc[i][1] += av[i]*wv.y;
        acc[i][2] += av[i]*wv.z; acc[i][3] += av[i]*wv.w;
      }
    }
    __syncthreads();
  }
  float b4[4];
  #pragma unroll
  for (int j = 0; j < 4; ++j) {
    float bv = 0.f;
    if (bias0) bv += bias0[nb + tx*4 + j];
    if (bias1) bv += bias1[nb + tx*4 + j];
    b4[j] = bv;
  }
  #pragma unroll
  for (int i = 0; i < 8; ++i) {
    float4 o;
    o.x = acc[i][0] + b4[0]; o.y = acc[i][1] + b4[1];
    o.z = acc[i][2] + b4[2]; o.w = acc[i][3] + b4[3];
    *(float4*)&C[(size_t)(mb + ty*8 + i) * ldc + nb + tx*4] = o;
  }
}

// ---------------- attention helper: block handles batch row b; writes ctx transposed ----
__device__ void attend_t(int b, const float* __restrict__ hvec, float* __restrict__ ctxdst,
                         const float* __restrict__ outbuf, const float* __restrict__ projo,
                         const int* __restrict__ mask, float* scratch, int tid)
{
  float* scp = scratch;        // 256
  float* scv = scratch + 256;  // 64
  const int tq = tid >> 2, dq = tid & 3;
  const float4* hv = (const float4*)(hvec + dq*256);
  const float4* pv = (const float4*)(projo + (size_t)(b*T + tq)*H2 + dq*256);
  float p = 0.f;
  #pragma unroll 8
  for (int k4 = 0; k4 < 64; ++k4) {
    float4 a = hv[k4], q = pv[k4];
    p += a.x*q.x + a.y*q.y + a.z*q.z + a.w*q.w;
  }
  scp[tid] = p;
  __syncthreads();
  if (tid < 64) {
    float v = scp[tid*4] + scp[tid*4+1] + scp[tid*4+2] + scp[tid*4+3];
    float mx = v;
    #pragma unroll
    for (int d = 32; d; d >>= 1) mx = fmaxf(mx, __shfl_xor(mx, d, 64));
    float e = expf(v - mx);
    float sm = e;
    #pragma unroll
    for (int d = 32; d; d >>= 1) sm += __shfl_xor(sm, d, 64);
    scv[tid] = e * (1.f / sm) * (float)mask[b*T + tid];
  }
  __syncthreads();
  float a0 = 0, a1 = 0, a2 = 0, a3 = 0;
  #pragma unroll 8
  for (int tt = 0; tt < 64; ++tt) {
    float pp = scv[tt];
    float4 o4 = *(const float4*)(outbuf + (size_t)(b*T + tt)*H2 + tid*4);
    a0 += pp*o4.x; a1 += pp*o4.y; a2 += pp*o4.z; a3 += pp*o4.w;
  }
  int k0 = tid*4;
  ctxdst[(k0+0)*32 + b] = a0;
  ctxdst[(k0+1)*32 + b] = a1;
  ctxdst[(k0+2)*32 + b] = a2;
  ctxdst[(k0+3)*32 + b] = a3;
}

// ---------------- persistent encoder: weights in registers (32 floats/thread) ----------
__global__ __launch_bounds__(256, 1) void encoder_persistent(
    const float* __restrict__ xg_f, const float* __restrict__ xg_b,
    const float* __restrict__ Whh_f, const float* __restrict__ Whh_b,
    const int* __restrict__ mask,
    float* __restrict__ hencT,    // [dir][2][512][32]
    float* __restrict__ outbuf,
    unsigned* __restrict__ eslots, unsigned* __restrict__ eflags)
{
  __shared__ float S_lds[2][128*36];
  __shared__ float pacc[2048];
  __shared__ float g_lds[512];
  const int blk = blockIdx.x, tid = threadIdx.x;
  const int lane = tid & 63, wv = tid >> 6;
  const int dir = blk >> 7, nd = blk & 127;
  const int hibase = nd * 4;
  const int jj = tid & 7, kk = tid >> 3;
  const float* xg  = dir ? xg_b : xg_f;
  const float* Whh = dir ? Whh_b : Whh_f;
  float* hbase = hencT + dir * 32768;

  float wge[2][16];
  #pragma unroll
  for (int p = 0; p < 2; ++p) {
    int jl = jj*2 + p;
    int j = (jl>>2)*512 + hibase + (jl&3);
    #pragma unroll
    for (int sc = 0; sc < 4; ++sc)
      #pragma unroll
      for (int i = 0; i < 4; ++i)
        wge[p][sc*4+i] = Whh[(size_t)j*512 + sc*128 + i*32 + kk];
  }
  float c_reg = 0.f;
  const int kr = tid >> 1, bh = (tid & 1) * 16;

  for (int tt = 0; tt < 64; ++tt) {
    const int t = dir ? (63 - tt) : tt;
    const float* hc = hbase + (tt & 1) * 16384;
    float* hn = hbase + ((tt + 1) & 1) * 16384;

    float a0[32], a1[32];
    #pragma unroll
    for (int q = 0; q < 32; ++q) { a0[q] = 0.f; a1[q] = 0.f; }

    float4 rr0, rr1, rr2, rr3;
    {
      const float4* p = (const float4*)(hc + kr*32 + bh);
      rr0 = p[0]; rr1 = p[1]; rr2 = p[2]; rr3 = p[3];
      float* d = &S_lds[0][kr*36 + bh];
      *(float4*)d = rr0; *(float4*)(d+4) = rr1; *(float4*)(d+8) = rr2; *(float4*)(d+12) = rr3;
    }
    __syncthreads();
    #pragma unroll
    for (int sc = 0; sc < 4; ++sc) {
      if (sc < 3) {
        const float4* p = (const float4*)(hc + (sc+1)*4096 + kr*32 + bh);
        rr0 = p[0]; rr1 = p[1]; rr2 = p[2]; rr3 = p[3];
      }
      const float* Sb = &S_lds[sc & 1][0];
      #pragma unroll
      for (int i = 0; i < 4; ++i) {
        const float* sp = Sb + (i*32 + kk)*36;
        float w0 = wge[0][sc*4+i], w1 = wge[1][sc*4+i];
        #pragma unroll
        for (int q = 0; q < 8; ++q) {
          float4 s4 = *(const float4*)(sp + q*4);
          a0[q*4+0] += w0*s4.x; a0[q*4+1] += w0*s4.y; a0[q*4+2] += w0*s4.z; a0[q*4+3] += w0*s4.w;
          a1[q*4+0] += w1*s4.x; a1[q*4+1] += w1*s4.y; a1[q*4+2] += w1*s4.z; a1[q*4+3] += w1*s4.w;
        }
      }
      if (sc < 3) {
        float* d = &S_lds[(sc+1) & 1][kr*36 + bh];
        *(float4*)d = rr0; *(float4*)(d+4) = rr1; *(float4*)(d+8) = rr2; *(float4*)(d+12) = rr3;
      }
      __syncthreads();
    }
    #pragma unroll
    for (int dd = 8; dd <= 32; dd <<= 1) {
      #pragma unroll
      for (int q = 0; q < 32; ++q) {
        a0[q] += __shfl_down(a0[q], dd, 64);
        a1[q] += __shfl_down(a1[q], dd, 64);
      }
    }
    if (lane < 8) {
      float* pw = &pacc[wv*512 + lane*64];
      #pragma unroll
      for (int q = 0; q < 32; ++q) { pw[q] = a0[q]; pw[32+q] = a1[q]; }
    }
    __syncthreads();
    #pragma unroll
    for (int r = 0; r < 2; ++r) {
      int o = tid + r*256;
      int jl = o >> 5, b = o & 31;
      int off = (jl>>1)*64 + (jl&1)*32 + b;
      float v = pacc[off] + pacc[512+off] + pacc[1024+off] + pacc[1536+off];
      v += xg[(size_t)(b*T + t)*2048 + (jl>>2)*512 + hibase + (jl&3)];
      g_lds[jl*32 + b] = v;
    }
    __syncthreads();
    if (tid < 128) {
      int hil = tid >> 5, b = tid & 31;
      float gi = g_lds[(0*4+hil)*32 + b];
      float gf = g_lds[(1*4+hil)*32 + b];
      float gg = g_lds[(2*4+hil)*32 + b];
      float go = g_lds[(3*4+hil)*32 + b];
      c_reg = sigm(gf)*c_reg + sigm(gi)*tanhf(gg);
      float h = sigm(go)*tanhf(c_reg);
      int hi = hibase + hil;
      hn[hi*32 + b] = h;
      outbuf[(size_t)(b*T + t)*H2 + dir*512 + hi] = h * (float)mask[b*T + t];
    }
    pbar(eslots + (dir*64 + tt)*128, eflags + (dir*64 + tt)*16, nd, 128);
  }
}

// ---------------- persistent decoder: gates weights in LDS, scores weights in regs ------
// Dynamic LDS (floats): Wg 16x2052=32832 | S2 2x64x36=4608 | pacc 2048 | g_lds 512
// total 40000 floats = 160000 B
__global__ __launch_bounds__(256, 1) void decoder_persistent(
    const float* __restrict__ basep, const float* __restrict__ tagp,
    const float* __restrict__ dWhh,  const float* __restrict__ dWih,
    const float* __restrict__ Wout,  const float* __restrict__ bout,
    const float* __restrict__ projo, const float* __restrict__ outbuf,
    const int* __restrict__ mask,
    float* __restrict__ hT,          // [2][1024][32]
    float* __restrict__ ctxT,        // [2][1024][32]
    float* __restrict__ hrow,        // [32][1024]
    unsigned long long* __restrict__ argslot,
    unsigned* __restrict__ dslots, unsigned* __restrict__ dflags,
    float* __restrict__ out)
{
  extern __shared__ float dyn[];
  float* Wg    = dyn;           // 32832
  float* S2    = dyn + 32832;   // 4608
  float* pacc  = dyn + 37440;   // 2048
  float* g_lds = dyn + 39488;   // 512

  const int blk = blockIdx.x, tid = threadIdx.x;
  const int lane = tid & 63, wv = tid >> 6;
  const int hibase = blk * 4;
  const int jj = tid & 7, kk = tid >> 3;     // gates mapping
  const int jl0 = jj*2, jl1 = jj*2 + 1;
  const int vv = tid & 3, kq = tid >> 2;     // scores mapping
  const int vbase = blk * 8;

  // ---- preload gates weights into LDS (once) ----
  for (int jl = 0; jl < 16; ++jl) {
    int j = (jl>>2)*1024 + hibase + (jl&3);
    #pragma unroll
    for (int r = 0; r < 2; ++r) {
      int c = tid*4 + r*1024;
      float4 w;
      if (c < 1024) w = *(const float4*)(dWhh + (size_t)j*1024 + c);
      else          w = *(const float4*)(dWih + (size_t)j*2560 + 512 + (c - 1024));
      *(float4*)&Wg[jl*2052 + c] = w;
    }
  }
  // ---- scores weights in registers (64 floats/thread) ----
  float ws0[32], ws1[32];
  {
    int v0 = vbase + vv*2;
    #pragma unroll
    for (int s2 = 0; s2 < 32; ++s2) {
      ws0[s2] = Wout[(size_t)(v0+0)*2048 + s2*64 + kq];
      ws1[s2] = Wout[(size_t)(v0+1)*2048 + s2*64 + kq];
    }
  }

  float c_reg = 0.f;
  int bslot = 0;

  // ---- prologue: context0 = attend(last_output) ----
  if (blk < 32) {
    int b = blk;
    int len = -1;
    for (int i = 0; i < T; ++i) len += mask[b*T + i];
    attend_t(b, outbuf + (size_t)(b*T + len)*H2, ctxT, outbuf, projo, mask, pacc, tid);
  }
  pbar(dslots + (bslot)*256, dflags + (bslot)*16, blk, 256); bslot++;

  const int sr = tid >> 2;          // staging row 0..63
  const int scol = (tid & 3) * 8;   // staging col {0,8,16,24}

  for (int t = 0; t < T; ++t) {
    const int cur = t & 1, nxt = cur ^ 1;
    const float* hTc  = hT + cur*32768;
    float*       hTn  = hT + nxt*32768;
    const float* ctxc = ctxT + cur*32768;
    float*       ctxn = ctxT + nxt*32768;

    // prefetch per-thread external gate contributions (base + tag embed proj)
    const int b_own = tid & 31;
    const int jlA = tid >> 5, jlB = jlA + 8;
    const int jA = (jlA>>2)*1024 + hibase + (jlA&3);
    const int jB = (jlB>>2)*1024 + hibase + (jlB&3);
    float extA = basep[(size_t)(b_own*T + t)*G4 + jA];
    float extB = basep[(size_t)(b_own*T + t)*G4 + jB];
    if (t > 0) {
      unsigned tg = ~(unsigned)argslot[((t+2)%3)*32 + b_own];
      extA += tagp[(size_t)tg*G4 + jA];
      extB += tagp[(size_t)tg*G4 + jB];
    }

    // ===== phase 1: gates (K=2048: h | ctx), weights from LDS =====
    float a0[32], a1[32];
    #pragma unroll
    for (int q = 0; q < 32; ++q) { a0[q] = 0.f; a1[q] = 0.f; }
    {
      const float* src = hTc + sr*32 + scol;
      *(float4*)&S2[sr*36 + scol]     = *(const float4*)src;
      *(float4*)&S2[sr*36 + scol + 4] = *(const float4*)(src + 4);
      __syncthreads();
      for (int sl = 0; sl < 32; ++sl) {
        const int cb = sl & 1, nb2 = cb ^ 1;
        float4 u0, u1;
        if (sl < 31) {   // issue next-slice load early (T14 split)
          int krr = (sl+1)*64 + sr;
          const float* bsrc = (krr < 1024) ? (hTc + krr*32) : (ctxc + (krr-1024)*32);
          u0 = *(const float4*)(bsrc + scol);
          u1 = *(const float4*)(bsrc + scol + 4);
        }
        const float* Sb = &S2[cb*2304];
        #pragma unroll
        for (int i = 0; i < 2; ++i) {
          float w0 = Wg[jl0*2052 + sl*64 + i*32 + kk];
          float w1 = Wg[jl1*2052 + sl*64 + i*32 + kk];
          const float* sp = Sb + (i*32 + kk)*36;
          #pragma unroll
          for (int q = 0; q < 8; ++q) {
            float4 s4 = *(const float4*)(sp + q*4);
            a0[q*4+0] += w0*s4.x; a0[q*4+1] += w0*s4.y; a0[q*4+2] += w0*s4.z; a0[q*4+3] += w0*s4.w;
            a1[q*4+0] += w1*s4.x; a1[q*4+1] += w1*s4.y; a1[q*4+2] += w1*s4.z; a1[q*4+3] += w1*s4.w;
          }
        }
        if (sl < 31) {   // LDS store after compute (waitcnt hidden under FMAs)
          *(float4*)&S2[nb2*2304 + sr*36 + scol]     = u0;
          *(float4*)&S2[nb2*2304 + sr*36 + scol + 4] = u1;
        }
        __syncthreads();
      }
    }
    #pragma unroll
    for (int dd = 8; dd <= 32; dd <<= 1) {
      #pragma unroll
      for (int q = 0; q < 32; ++q) {
        a0[q] += __shfl_down(a0[q], dd, 64);
        a1[q] += __shfl_down(a1[q], dd, 64);
      }
    }
    if (lane < 8) {
      float* pw = &pacc[wv*512 + lane*64];
      #pragma unroll
      for (int q = 0; q < 32; ++q) { pw[q] = a0[q]; pw[32+q] = a1[q]; }
    }
    __syncthreads();
    #pragma unroll
    for (int r = 0; r < 2; ++r) {
      int o = tid + r*256;
      int jl = o >> 5, b = o & 31;
      int off = (jl>>1)*64 + (jl&1)*32 + b;
      float vsum = pacc[off] + pacc[512+off] + pacc[1024+off] + pacc[1536+off];
      vsum += (r == 0) ? extA : extB;
      g_lds[jl*32 + b] = vsum;
    }
    __syncthreads();
    if (tid < 128) {
      int hil = tid >> 5, b = tid & 31;
      float gi = g_lds[(0*4+hil)*32 + b];
      float gf = g_lds[(1*4+hil)*32 + b];
      float gg = g_lds[(2*4+hil)*32 + b];
      float go = g_lds[(3*4+hil)*32 + b];
      c_reg = sigm(gf)*c_reg + sigm(gi)*tanhf(gg);
      float h = sigm(go)*tanhf(c_reg);
      int hi = hibase + hil;
      hTn[hi*32 + b] = h;
      hrow[b*1024 + hi] = h;
    }
    pbar(dslots + (bslot)*256, dflags + (bslot)*16, blk, 256); bslot++;

    // ===== phase 2: scores (K=2048: h_new | ctx_old), weights in regs =====
    #pragma unroll
    for (int q = 0; q < 32; ++q) { a0[q] = 0.f; a1[q] = 0.f; }
    {
      const float* src = hTn + sr*32 + scol;
      *(float4*)&S2[sr*36 + scol]     = *(const float4*)src;
      *(float4*)&S2[sr*36 + scol + 4] = *(const float4*)(src + 4);
      __syncthreads();
      #pragma unroll
      for (int sl = 0; sl < 32; ++sl) {
        const int cb = sl & 1, nb2 = cb ^ 1;
        float4 u0, u1;
        if (sl < 31) {
          int krr = (sl+1)*64 + sr;
          const float* bsrc = (krr < 1024) ? (hTn + krr*32) : (ctxc + (krr-1024)*32);
          u0 = *(const float4*)(bsrc + scol);
          u1 = *(const float4*)(bsrc + scol + 4);
        }
        const float* sp = &S2[cb*2304] + kq*36;
        float w0 = ws0[sl], w1 = ws1[sl];
        #pragma unroll
        for (int q = 0; q < 8; ++q) {
          float4 s4 = *(const float4*)(sp + q*4);
          a0[q*4+0] += w0*s4.x; a0[q*4+1] += w0*s4.y; a0[q*4+2] += w0*s4.z; a0[q*4+3] += w0*s4.w;
          a1[q*4+0] += w1*s4.x; a1[q*4+1] += w1*s4.y; a1[q*4+2] += w1*s4.z; a1[q*4+3] += w1*s4.w;
        }
        if (sl < 31) {
          *(float4*)&S2[nb2*2304 + sr*36 + scol]     = u0;
          *(float4*)&S2[nb2*2304 + sr*36 + scol + 4] = u1;
        }
        __syncthreads();
      }
    }
    #pragma unroll
    for (int dd = 4; dd <= 32; dd <<= 1) {
      #pragma unroll
      for (int q = 0; q < 32; ++q) {
        a0[q] += __shfl_down(a0[q], dd, 64);
        a1[q] += __shfl_down(a1[q], dd, 64);
      }
    }
    if (lane < 4) {
      float* pw = &pacc[wv*256 + lane*64];
      #pragma unroll
      for (int q = 0; q < 32; ++q) { pw[q] = a0[q]; pw[32+q] = a1[q]; }
    }
    __syncthreads();
    {
      int vl = tid & 7, b = tid >> 3;
      int off = (vl>>1)*64 + (vl&1)*32 + b;
      float s = pacc[off] + pacc[256+off] + pacc[512+off] + pacc[768+off];
      s += bout[vbase + vl];
      out[(size_t)(b*T + t)*V + vbase + vl] = s;
      g_lds[vl*32 + b] = s;
    }
    __syncthreads();
    if (tid < 32) {
      int b = tid;
      float best = g_lds[b]; int bi = 0;
      #pragma unroll
      for (int vl = 1; vl < 8; ++vl) {
        float s = g_lds[vl*32 + b];
        if (s > best) { best = s; bi = vl; }
      }
      unsigned long long e = ((unsigned long long)fenc(best) << 32)
                           | (unsigned long long)(unsigned)(~(unsigned)(vbase + bi));
      atomicMax(&argslot[(t%3)*32 + b], e);
    } else if (blk == 0 && tid >= 32 && tid < 64) {
      argslot[((t+1)%3)*32 + (tid - 32)] = 0ull;
    }
    if (blk < 32) {
      __syncthreads();
      attend_t(blk, hrow + blk*1024, ctxn, outbuf, projo, mask, pacc, tid);
    }
    pbar(dslots + (bslot)*256, dflags + (bslot)*16, blk, 256); bslot++;
  }
}

// ---------------- host launch ----------------
extern "C" void kernel_launch(void* const* d_in, const int* in_sizes, int n_in,
                              void* d_out, int out_size, void* d_ws, size_t ws_size,
                              hipStream_t stream)
{
  (void)in_sizes; (void)n_in; (void)out_size; (void)ws_size;
  const float* emb    = (const float*)d_in[0];
  const int*   mask   = (const int*)d_in[1];
  const float* Wih_f  = (const float*)d_in[2];
  const float* Whh_f  = (const float*)d_in[3];
  const float* bih_f  = (const float*)d_in[4];
  const float* bhh_f  = (const float*)d_in[5];
  const float* Wih_b  = (const float*)d_in[6];
  const float* Whh_b  = (const float*)d_in[7];
  const float* bih_b  = (const float*)d_in[8];
  const float* bhh_b  = (const float*)d_in[9];
  const float* attnW  = (const float*)d_in[10];
  const float* tagemb = (const float*)d_in[12];
  const float* dWih   = (const float*)d_in[13];
  const float* dWhh   = (const float*)d_in[14];
  const float* dbih   = (const float*)d_in[15];
  const float* dbhh   = (const float*)d_in[16];
  const float* Wout   = (const float*)d_in[17];
  const float* bout   = (const float*)d_in[18];
  float* out = (float*)d_out;

  float* ws = (float*)d_ws;
  float* xg_f   = ws + 0;          // 4194304
  float* xg_b   = ws + 4194304;    // 4194304
  float* outbuf = ws + 8388608;    // 2097152
  float* projo  = ws + 10485760;   // 2097152
  float* basep  = ws + 12582912;   // 8388608
  float* tagp   = ws + 20971520;   // 8388608
  // --- zeroed state block ---
  float* hT     = ws + 29360128;   // 65536  [2][1024][32]
  float* ctxT   = ws + 29425664;   // 65536  [2][1024][32]
  float* hrow   = ws + 29491200;   // 32768
  float* hencT  = ws + 29523968;   // 65536  [2][2][512][32]
  unsigned long long* argslot = (unsigned long long*)(ws + 29589504);  // 96 u64 (192 fl)
  unsigned* dslots = (unsigned*)(ws + 29589696);   // 129*256 = 33024 u32
  unsigned* dflags = (unsigned*)(ws + 29622720);   // 129*16  = 2064 u32
  unsigned* eslots = (unsigned*)(ws + 29624784);   // 128*128 = 16384 u32
  unsigned* eflags = (unsigned*)(ws + 29641168);   // 128*16  = 2048 u32
  // end: 29643216 floats

  // allow 160000 B dynamic LDS for the decoder
  (void)hipFuncSetAttribute((const void*)decoder_persistent,
                            hipFuncAttributeMaxDynamicSharedMemorySize, 160000);

  // zero all persistent-kernel state every call (graph-replay deterministic)
  hipMemsetAsync((void*)(ws + 29360128), 0, (size_t)(29643216 - 29360128) * sizeof(float), stream);

  // xg = emb @ Wih^T + bih + bhh   (M=2048, N=2048, K=512)
  gemm_nt<<<dim3(32, 16), 256, 0, stream>>>(emb, 512, Wih_f, 512, xg_f, 2048, bih_f, bhh_f, 512);
  gemm_nt<<<dim3(32, 16), 256, 0, stream>>>(emb, 512, Wih_b, 512, xg_b, 2048, bih_b, bhh_b, 512);
  // tagp = tag_embed @ dec_Wih[:, :512]^T   (M=2048, N=4096, K=512)
  gemm_nt<<<dim3(64, 16), 256, 0, stream>>>(tagemb, 512, dWih, DEC_IN, tagp, G4, nullptr, nullptr, 512);
  // encoder scan (persistent, register-resident Whh)
  encoder_persistent<<<256, 256, 0, stream>>>(xg_f, xg_b, Whh_f, Whh_b, mask, hencT, outbuf, eslots, eflags);
  // projo[bt,d] = sum_e attn_W[d,e]*output[bt,e]   (M=2048, N=1024, K=1024)
  gemm_nt<<<dim3(16, 16), 256, 0, stream>>>(outbuf, H2, attnW, H2, projo, H2, nullptr, nullptr, H2);
  // basep = aligned @ dec_Wih[:,1536:]^T + dbih + dbhh   (M=2048, N=4096, K=1024)
  gemm_nt<<<dim3(64, 16), 256, 0, stream>>>(outbuf, H2, dWih + 1536, DEC_IN, basep, G4, dbih, dbhh, H2);
  // persistent decoder
  decoder_persistent<<<256, 256, 160000, stream>>>(basep, tagp, dWhh, dWih, Wout, bout,
                                                   projo, outbuf, mask, hT, ctxT, hrow,
                                                   argslot, dslots, dflags, out);
}

// Round 7
// 6248.499 us; speedup vs baseline: 2.1429x; 1.0378x over previous
//
#include <hip/hip_runtime.h>

#define B   32
#define T   64
#define D   512
#define H   512
#define H2  1024
#define G4  4096
#define V   2048
#define DEC_IN 2560

__device__ __forceinline__ float sigm(float x) { return 1.f / (1.f + expf(-x)); }

__device__ __forceinline__ unsigned fenc(float f) {
  unsigned u = __float_as_uint(f);
  return (u & 0x80000000u) ? ~u : (u | 0x80000000u);
}

// ---- store-based parallel grid barrier (no RMW serialization) ----
__device__ __forceinline__ void pbar(unsigned* slots, unsigned* flag, int myid, int nblk) {
  __syncthreads();
  if (threadIdx.x == 0)
    __hip_atomic_store(slots + myid, 1u, __ATOMIC_RELEASE, __HIP_MEMORY_SCOPE_AGENT);
  if (myid == 0) {
    for (int s = threadIdx.x; s < nblk; s += 256) {
      while (!__hip_atomic_load(slots + s, __ATOMIC_RELAXED, __HIP_MEMORY_SCOPE_AGENT))
        __builtin_amdgcn_s_sleep(1);
    }
    __syncthreads();
    if (threadIdx.x == 0)
      __hip_atomic_store(flag, 1u, __ATOMIC_RELEASE, __HIP_MEMORY_SCOPE_AGENT);
  }
  if (threadIdx.x == 0) {
    while (!__hip_atomic_load(flag, __ATOMIC_RELAXED, __HIP_MEMORY_SCOPE_AGENT))
      __builtin_amdgcn_s_sleep(1);
    (void)__hip_atomic_load(flag, __ATOMIC_ACQUIRE, __HIP_MEMORY_SCOPE_AGENT);
  }
  __syncthreads();
}

// ---------------- generic fp32 GEMM:  C[m,n] = sum_k A[m,k]*W[n,k] + bias0[n] + bias1[n]
__global__ __launch_bounds__(256) void gemm_nt(
    const float* __restrict__ A, int lda,
    const float* __restrict__ W, int ldw,
    float* __restrict__ C, int ldc,
    const float* __restrict__ bias0, const float* __restrict__ bias1,
    int K)
{
  __shared__ float As[16][132];
  __shared__ float Ws[16][68];
  const int tid = threadIdx.x;
  const int nb = blockIdx.x * 64;
  const int mb = blockIdx.y * 128;
  const int tx = tid & 15;
  const int ty = tid >> 4;
  float acc[8][4] = {};

  const int am = tid >> 1, ak = (tid & 1) * 8;
  const int wn = tid >> 2, wk = (tid & 3) * 4;
  const float* aptr = A + (size_t)(mb + am) * lda + ak;
  const float* wptr = W + (size_t)(nb + wn) * ldw + wk;

  for (int k0 = 0; k0 < K; k0 += 16) {
    float4 u = *(const float4*)(aptr + k0);
    float4 v = *(const float4*)(aptr + k0 + 4);
    float4 w = *(const float4*)(wptr + k0);
    As[ak+0][am] = u.x; As[ak+1][am] = u.y; As[ak+2][am] = u.z; As[ak+3][am] = u.w;
    As[ak+4][am] = v.x; As[ak+5][am] = v.y; As[ak+6][am] = v.z; As[ak+7][am] = v.w;
    Ws[wk+0][wn] = w.x; Ws[wk+1][wn] = w.y; Ws[wk+2][wn] = w.z; Ws[wk+3][wn] = w.w;
    __syncthreads();
    #pragma unroll
    for (int k = 0; k < 16; ++k) {
      float4 a0 = *(const float4*)&As[k][ty*8];
      float4 a1 = *(const float4*)&As[k][ty*8+4];
      float4 wv = *(const float4*)&Ws[k][tx*4];
      float av[8] = {a0.x,a0.y,a0.z,a0.w,a1.x,a1.y,a1.z,a1.w};
      #pragma unroll
      for (int i = 0; i < 8; ++i) {
        acc[i][0] += av[i]*wv.x; acc[i][1] += av[i]*wv.y;
        acc[i][2] += av[i]*wv.z; acc[i][3] += av[i]*wv.w;
      }
    }
    __syncthreads();
  }
  float b4[4];
  #pragma unroll
  for (int j = 0; j < 4; ++j) {
    float bv = 0.f;
    if (bias0) bv += bias0[nb + tx*4 + j];
    if (bias1) bv += bias1[nb + tx*4 + j];
    b4[j] = bv;
  }
  #pragma unroll
  for (int i = 0; i < 8; ++i) {
    float4 o;
    o.x = acc[i][0] + b4[0]; o.y = acc[i][1] + b4[1];
    o.z = acc[i][2] + b4[2]; o.w = acc[i][3] + b4[3];
    *(float4*)&C[(size_t)(mb + ty*8 + i) * ldc + nb + tx*4] = o;
  }
}

// ---------------- attention helper ----------------
__device__ void attend_t(int b, const float* __restrict__ hvec, float* __restrict__ ctxdst,
                         const float* __restrict__ outbuf, const float* __restrict__ projo,
                         const int* __restrict__ mask, float* scratch, int tid)
{
  float* scp = scratch;        // 256
  float* scv = scratch + 256;  // 64
  const int tq = tid >> 2, dq = tid & 3;
  const float4* hv = (const float4*)(hvec + dq*256);
  const float4* pv = (const float4*)(projo + (size_t)(b*T + tq)*H2 + dq*256);
  float p = 0.f;
  #pragma unroll 8
  for (int k4 = 0; k4 < 64; ++k4) {
    float4 a = hv[k4], q = pv[k4];
    p += a.x*q.x + a.y*q.y + a.z*q.z + a.w*q.w;
  }
  scp[tid] = p;
  __syncthreads();
  if (tid < 64) {
    float v = scp[tid*4] + scp[tid*4+1] + scp[tid*4+2] + scp[tid*4+3];
    float mx = v;
    #pragma unroll
    for (int d = 32; d; d >>= 1) mx = fmaxf(mx, __shfl_xor(mx, d, 64));
    float e = expf(v - mx);
    float sm = e;
    #pragma unroll
    for (int d = 32; d; d >>= 1) sm += __shfl_xor(sm, d, 64);
    scv[tid] = e * (1.f / sm) * (float)mask[b*T + tid];
  }
  __syncthreads();
  float a0 = 0, a1 = 0, a2 = 0, a3 = 0;
  #pragma unroll 8
  for (int tt = 0; tt < 64; ++tt) {
    float pp = scv[tt];
    float4 o4 = *(const float4*)(outbuf + (size_t)(b*T + tt)*H2 + tid*4);
    a0 += pp*o4.x; a1 += pp*o4.y; a2 += pp*o4.z; a3 += pp*o4.w;
  }
  int k0 = tid*4;
  ctxdst[(k0+0)*32 + b] = a0;
  ctxdst[(k0+1)*32 + b] = a1;
  ctxdst[(k0+2)*32 + b] = a2;
  ctxdst[(k0+3)*32 + b] = a3;
}

// ---------------- persistent encoder (unchanged from R6) ----------
__global__ __launch_bounds__(256, 1) void encoder_persistent(
    const float* __restrict__ xg_f, const float* __restrict__ xg_b,
    const float* __restrict__ Whh_f, const float* __restrict__ Whh_b,
    const int* __restrict__ mask,
    float* __restrict__ hencT,    // [dir][2][512][32]
    float* __restrict__ outbuf,
    unsigned* __restrict__ eslots, unsigned* __restrict__ eflags)
{
  __shared__ float S_lds[2][128*36];
  __shared__ float pacc[2048];
  __shared__ float g_lds[512];
  const int blk = blockIdx.x, tid = threadIdx.x;
  const int lane = tid & 63, wv = tid >> 6;
  const int dir = blk >> 7, nd = blk & 127;
  const int hibase = nd * 4;
  const int jj = tid & 7, kk = tid >> 3;
  const float* xg  = dir ? xg_b : xg_f;
  const float* Whh = dir ? Whh_b : Whh_f;
  float* hbase = hencT + dir * 32768;

  float wge[2][16];
  #pragma unroll
  for (int p = 0; p < 2; ++p) {
    int jl = jj*2 + p;
    int j = (jl>>2)*512 + hibase + (jl&3);
    #pragma unroll
    for (int sc = 0; sc < 4; ++sc)
      #pragma unroll
      for (int i = 0; i < 4; ++i)
        wge[p][sc*4+i] = Whh[(size_t)j*512 + sc*128 + i*32 + kk];
  }
  float c_reg = 0.f;
  const int kr = tid >> 1, bh = (tid & 1) * 16;

  for (int tt = 0; tt < 64; ++tt) {
    const int t = dir ? (63 - tt) : tt;
    const float* hc = hbase + (tt & 1) * 16384;
    float* hn = hbase + ((tt + 1) & 1) * 16384;

    float a0[32], a1[32];
    #pragma unroll
    for (int q = 0; q < 32; ++q) { a0[q] = 0.f; a1[q] = 0.f; }

    float4 rr0, rr1, rr2, rr3;
    {
      const float4* p = (const float4*)(hc + kr*32 + bh);
      rr0 = p[0]; rr1 = p[1]; rr2 = p[2]; rr3 = p[3];
      float* d = &S_lds[0][kr*36 + bh];
      *(float4*)d = rr0; *(float4*)(d+4) = rr1; *(float4*)(d+8) = rr2; *(float4*)(d+12) = rr3;
    }
    __syncthreads();
    #pragma unroll
    for (int sc = 0; sc < 4; ++sc) {
      if (sc < 3) {
        const float4* p = (const float4*)(hc + (sc+1)*4096 + kr*32 + bh);
        rr0 = p[0]; rr1 = p[1]; rr2 = p[2]; rr3 = p[3];
      }
      const float* Sb = &S_lds[sc & 1][0];
      #pragma unroll
      for (int i = 0; i < 4; ++i) {
        const float* sp = Sb + (i*32 + kk)*36;
        float w0 = wge[0][sc*4+i], w1 = wge[1][sc*4+i];
        #pragma unroll
        for (int q = 0; q < 8; ++q) {
          float4 s4 = *(const float4*)(sp + q*4);
          a0[q*4+0] += w0*s4.x; a0[q*4+1] += w0*s4.y; a0[q*4+2] += w0*s4.z; a0[q*4+3] += w0*s4.w;
          a1[q*4+0] += w1*s4.x; a1[q*4+1] += w1*s4.y; a1[q*4+2] += w1*s4.z; a1[q*4+3] += w1*s4.w;
        }
      }
      if (sc < 3) {
        float* d = &S_lds[(sc+1) & 1][kr*36 + bh];
        *(float4*)d = rr0; *(float4*)(d+4) = rr1; *(float4*)(d+8) = rr2; *(float4*)(d+12) = rr3;
      }
      __syncthreads();
    }
    #pragma unroll
    for (int dd = 8; dd <= 32; dd <<= 1) {
      #pragma unroll
      for (int q = 0; q < 32; ++q) {
        a0[q] += __shfl_down(a0[q], dd, 64);
        a1[q] += __shfl_down(a1[q], dd, 64);
      }
    }
    if (lane < 8) {
      float* pw = &pacc[wv*512 + lane*64];
      #pragma unroll
      for (int q = 0; q < 32; ++q) { pw[q] = a0[q]; pw[32+q] = a1[q]; }
    }
    __syncthreads();
    #pragma unroll
    for (int r = 0; r < 2; ++r) {
      int o = tid + r*256;
      int jl = o >> 5, b = o & 31;
      int off = (jl>>1)*64 + (jl&1)*32 + b;
      float v = pacc[off] + pacc[512+off] + pacc[1024+off] + pacc[1536+off];
      v += xg[(size_t)(b*T + t)*2048 + (jl>>2)*512 + hibase + (jl&3)];
      g_lds[jl*32 + b] = v;
    }
    __syncthreads();
    if (tid < 128) {
      int hil = tid >> 5, b = tid & 31;
      float gi = g_lds[(0*4+hil)*32 + b];
      float gf = g_lds[(1*4+hil)*32 + b];
      float gg = g_lds[(2*4+hil)*32 + b];
      float go = g_lds[(3*4+hil)*32 + b];
      c_reg = sigm(gf)*c_reg + sigm(gi)*tanhf(gg);
      float h = sigm(go)*tanhf(c_reg);
      int hi = hibase + hil;
      hn[hi*32 + b] = h;
      outbuf[(size_t)(b*T + t)*H2 + dir*512 + hi] = h * (float)mask[b*T + t];
    }
    pbar(eslots + (dir*64 + tt)*128, eflags + (dir*64 + tt)*16, nd, 128);
  }
}

// ---- decoder K-loop macros: 4-deep register prefetch queue ----
#define LD1(qq, s) { int krr = (s)*64 + sr; \
  const float* bsrc = (krr < 1024) ? (hTc + krr*32) : (ctxc + (krr-1024)*32); \
  qq##a = *(const float4*)(bsrc + scol); qq##b = *(const float4*)(bsrc + scol + 4); }
#define LD2(qq, s) { int krr = (s)*64 + sr; \
  const float* bsrc = (krr < 1024) ? (hTn + krr*32) : (ctxc + (krr-1024)*32); \
  qq##a = *(const float4*)(bsrc + scol); qq##b = *(const float4*)(bsrc + scol + 4); }
#define ST(qq, OFF) { *(float4*)&S2[(OFF) + sr*36 + scol] = qq##a; \
  *(float4*)&S2[(OFF) + sr*36 + scol + 4] = qq##b; }
#define COMP1(sl, OFF) { const float* Sb = &S2[(OFF)]; \
  _Pragma("unroll") for (int i = 0; i < 2; ++i) { \
    float w0 = Wg[jl0*2052 + (sl)*64 + i*32 + kk]; \
    float w1 = Wg[jl1*2052 + (sl)*64 + i*32 + kk]; \
    const float* sp = Sb + (i*32 + kk)*36; \
    _Pragma("unroll") for (int q = 0; q < 8; ++q) { \
      float4 s4 = *(const float4*)(sp + q*4); \
      a0[q*4+0] += w0*s4.x; a0[q*4+1] += w0*s4.y; a0[q*4+2] += w0*s4.z; a0[q*4+3] += w0*s4.w; \
      a1[q*4+0] += w1*s4.x; a1[q*4+1] += w1*s4.y; a1[q*4+2] += w1*s4.z; a1[q*4+3] += w1*s4.w; } } }
#define COMP2(sl, OFF) { const float* sp = &S2[(OFF)] + kq*36; \
  float w0 = ws0[sl], w1 = ws1[sl]; \
  _Pragma("unroll") for (int q = 0; q < 8; ++q) { \
    float4 s4 = *(const float4*)(sp + q*4); \
    a0[q*4+0] += w0*s4.x; a0[q*4+1] += w0*s4.y; a0[q*4+2] += w0*s4.z; a0[q*4+3] += w0*s4.w; \
    a1[q*4+0] += w1*s4.x; a1[q*4+1] += w1*s4.y; a1[q*4+2] += w1*s4.z; a1[q*4+3] += w1*s4.w; } }

// ---------------- persistent decoder: gates weights in LDS, scores weights in regs ------
// Dynamic LDS (floats): Wg 16x2052=32832 | S2 2x64x36=4608 | pacc 2048 | g_lds 512
__global__ __launch_bounds__(256, 1) void decoder_persistent(
    const float* __restrict__ basep, const float* __restrict__ tagp,
    const float* __restrict__ dWhh,  const float* __restrict__ dWih,
    const float* __restrict__ Wout,  const float* __restrict__ bout,
    const float* __restrict__ projo, const float* __restrict__ outbuf,
    const int* __restrict__ mask,
    float* __restrict__ hT,          // [2][1024][32]
    float* __restrict__ ctxT,        // [2][1024][32]
    float* __restrict__ hrow,        // [32][1024]
    unsigned long long* __restrict__ argslot,
    unsigned* __restrict__ dslots, unsigned* __restrict__ dflags,
    float* __restrict__ out)
{
  extern __shared__ float dyn[];
  float* Wg    = dyn;           // 32832
  float* S2    = dyn + 32832;   // 4608
  float* pacc  = dyn + 37440;   // 2048
  float* g_lds = dyn + 39488;   // 512

  const int blk = blockIdx.x, tid = threadIdx.x;
  const int lane = tid & 63, wv = tid >> 6;
  const int hibase = blk * 4;
  const int jj = tid & 7, kk = tid >> 3;     // gates mapping
  const int jl0 = jj*2, jl1 = jj*2 + 1;
  const int vv = tid & 3, kq = tid >> 2;     // scores mapping
  const int vbase = blk * 8;

  // ---- preload gates weights into LDS (once) ----
  for (int jl = 0; jl < 16; ++jl) {
    int j = (jl>>2)*1024 + hibase + (jl&3);
    #pragma unroll
    for (int r = 0; r < 2; ++r) {
      int c = tid*4 + r*1024;
      float4 w;
      if (c < 1024) w = *(const float4*)(dWhh + (size_t)j*1024 + c);
      else          w = *(const float4*)(dWih + (size_t)j*2560 + 512 + (c - 1024));
      *(float4*)&Wg[jl*2052 + c] = w;
    }
  }
  // ---- scores weights in registers (64 floats/thread) ----
  float ws0[32], ws1[32];
  {
    int v0 = vbase + vv*2;
    #pragma unroll
    for (int s2 = 0; s2 < 32; ++s2) {
      ws0[s2] = Wout[(size_t)(v0+0)*2048 + s2*64 + kq];
      ws1[s2] = Wout[(size_t)(v0+1)*2048 + s2*64 + kq];
    }
  }

  float c_reg = 0.f;
  int bslot = 0;

  // ---- prologue: context0 = attend(last_output) ----
  if (blk < 32) {
    int b = blk;
    int len = -1;
    for (int i = 0; i < T; ++i) len += mask[b*T + i];
    attend_t(b, outbuf + (size_t)(b*T + len)*H2, ctxT, outbuf, projo, mask, pacc, tid);
  }
  pbar(dslots + (bslot)*256, dflags + (bslot)*16, blk, 256); bslot++;

  const int sr = tid >> 2;          // staging row 0..63
  const int scol = (tid & 3) * 8;   // staging col {0,8,16,24}

  for (int t = 0; t < T; ++t) {
    const int cur = t & 1, nxt = cur ^ 1;
    const float* hTc  = hT + cur*32768;
    float*       hTn  = hT + nxt*32768;
    const float* ctxc = ctxT + cur*32768;
    float*       ctxn = ctxT + nxt*32768;

    // prefetch per-thread external gate contributions (base + tag embed proj)
    const int b_own = tid & 31;
    const int jlA = tid >> 5, jlB = jlA + 8;
    const int jA = (jlA>>2)*1024 + hibase + (jlA&3);
    const int jB = (jlB>>2)*1024 + hibase + (jlB&3);
    float extA = basep[(size_t)(b_own*T + t)*G4 + jA];
    float extB = basep[(size_t)(b_own*T + t)*G4 + jB];
    if (t > 0) {
      unsigned tg = ~(unsigned)argslot[((t+2)%3)*32 + b_own];
      extA += tagp[(size_t)tg*G4 + jA];
      extB += tagp[(size_t)tg*G4 + jB];
    }

    // ===== phase 1: gates (K=2048: h | ctx), 4-deep register prefetch =====
    float a0[32], a1[32];
    #pragma unroll
    for (int q = 0; q < 32; ++q) { a0[q] = 0.f; a1[q] = 0.f; }
    {
      float4 q0a,q0b,q1a,q1b,q2a,q2b,q3a,q3b;
      LD1(q0, 0) LD1(q1, 1) LD1(q2, 2) LD1(q3, 3)
      ST(q0, 0)
      __syncthreads();
      for (int g = 0; g < 8; ++g) {
        const int sl = g*4;
        if (sl+4 < 32) LD1(q0, sl+4)
        COMP1(sl, 0)
        ST(q1, 2304)
        __syncthreads();
        if (sl+5 < 32) LD1(q1, sl+5)
        COMP1(sl+1, 2304)
        ST(q2, 0)
        __syncthreads();
        if (sl+6 < 32) LD1(q2, sl+6)
        COMP1(sl+2, 0)
        ST(q3, 2304)
        __syncthreads();
        if (sl+7 < 32) LD1(q3, sl+7)
        COMP1(sl+3, 2304)
        if (sl+4 < 32) ST(q0, 0)
        __syncthreads();
      }
    }
    #pragma unroll
    for (int dd = 8; dd <= 32; dd <<= 1) {
      #pragma unroll
      for (int q = 0; q < 32; ++q) {
        a0[q] += __shfl_down(a0[q], dd, 64);
        a1[q] += __shfl_down(a1[q], dd, 64);
      }
    }
    if (lane < 8) {
      float* pw = &pacc[wv*512 + lane*64];
      #pragma unroll
      for (int q = 0; q < 32; ++q) { pw[q] = a0[q]; pw[32+q] = a1[q]; }
    }
    __syncthreads();
    #pragma unroll
    for (int r = 0; r < 2; ++r) {
      int o = tid + r*256;
      int jl = o >> 5, b = o & 31;
      int off = (jl>>1)*64 + (jl&1)*32 + b;
      float vsum = pacc[off] + pacc[512+off] + pacc[1024+off] + pacc[1536+off];
      vsum += (r == 0) ? extA : extB;
      g_lds[jl*32 + b] = vsum;
    }
    __syncthreads();
    if (tid < 128) {
      int hil = tid >> 5, b = tid & 31;
      float gi = g_lds[(0*4+hil)*32 + b];
      float gf = g_lds[(1*4+hil)*32 + b];
      float gg = g_lds[(2*4+hil)*32 + b];
      float go = g_lds[(3*4+hil)*32 + b];
      c_reg = sigm(gf)*c_reg + sigm(gi)*tanhf(gg);
      float h = sigm(go)*tanhf(c_reg);
      int hi = hibase + hil;
      hTn[hi*32 + b] = h;
      hrow[b*1024 + hi] = h;
    }
    pbar(dslots + (bslot)*256, dflags + (bslot)*16, blk, 256); bslot++;

    // ===== phase 2: scores (K=2048: h_new | ctx_old), 4-deep register prefetch =====
    #pragma unroll
    for (int q = 0; q < 32; ++q) { a0[q] = 0.f; a1[q] = 0.f; }
    {
      float4 q0a,q0b,q1a,q1b,q2a,q2b,q3a,q3b;
      LD2(q0, 0) LD2(q1, 1) LD2(q2, 2) LD2(q3, 3)
      ST(q0, 0)
      __syncthreads();
      #pragma unroll
      for (int g = 0; g < 8; ++g) {
        const int sl = g*4;
        if (sl+4 < 32) LD2(q0, sl+4)
        COMP2(sl, 0)
        ST(q1, 2304)
        __syncthreads();
        if (sl+5 < 32) LD2(q1, sl+5)
        COMP2(sl+1, 2304)
        ST(q2, 0)
        __syncthreads();
        if (sl+6 < 32) LD2(q2, sl+6)
        COMP2(sl+2, 0)
        ST(q3, 2304)
        __syncthreads();
        if (sl+7 < 32) LD2(q3, sl+7)
        COMP2(sl+3, 2304)
        if (sl+4 < 32) ST(q0, 0)
        __syncthreads();
      }
    }
    #pragma unroll
    for (int dd = 4; dd <= 32; dd <<= 1) {
      #pragma unroll
      for (int q = 0; q < 32; ++q) {
        a0[q] += __shfl_down(a0[q], dd, 64);
        a1[q] += __shfl_down(a1[q], dd, 64);
      }
    }
    if (lane < 4) {
      float* pw = &pacc[wv*256 + lane*64];
      #pragma unroll
      for (int q = 0; q < 32; ++q) { pw[q] = a0[q]; pw[32+q] = a1[q]; }
    }
    __syncthreads();
    {
      int vl = tid & 7, b = tid >> 3;
      int off = (vl>>1)*64 + (vl&1)*32 + b;
      float s = pacc[off] + pacc[256+off] + pacc[512+off] + pacc[768+off];
      s += bout[vbase + vl];
      out[(size_t)(b*T + t)*V + vbase + vl] = s;
      g_lds[vl*32 + b] = s;
    }
    __syncthreads();
    if (tid < 32) {
      int b = tid;
      float best = g_lds[b]; int bi = 0;
      #pragma unroll
      for (int vl = 1; vl < 8; ++vl) {
        float s = g_lds[vl*32 + b];
        if (s > best) { best = s; bi = vl; }
      }
      unsigned long long e = ((unsigned long long)fenc(best) << 32)
                           | (unsigned long long)(unsigned)(~(unsigned)(vbase + bi));
      atomicMax(&argslot[(t%3)*32 + b], e);
    } else if (blk == 0 && tid >= 32 && tid < 64) {
      argslot[((t+1)%3)*32 + (tid - 32)] = 0ull;
    }
    if (blk < 32) {
      __syncthreads();
      attend_t(blk, hrow + blk*1024, ctxn, outbuf, projo, mask, pacc, tid);
    }
    pbar(dslots + (bslot)*256, dflags + (bslot)*16, blk, 256); bslot++;
  }
}

// ---------------- host launch ----------------
extern "C" void kernel_launch(void* const* d_in, const int* in_sizes, int n_in,
                              void* d_out, int out_size, void* d_ws, size_t ws_size,
                              hipStream_t stream)
{
  (void)in_sizes; (void)n_in; (void)out_size; (void)ws_size;
  const float* emb    = (const float*)d_in[0];
  const int*   mask   = (const int*)d_in[1];
  const float* Wih_f  = (const float*)d_in[2];
  const float* Whh_f  = (const float*)d_in[3];
  const float* bih_f  = (const float*)d_in[4];
  const float* bhh_f  = (const float*)d_in[5];
  const float* Wih_b  = (const float*)d_in[6];
  const float* Whh_b  = (const float*)d_in[7];
  const float* bih_b  = (const float*)d_in[8];
  const float* bhh_b  = (const float*)d_in[9];
  const float* attnW  = (const float*)d_in[10];
  const float* tagemb = (const float*)d_in[12];
  const float* dWih   = (const float*)d_in[13];
  const float* dWhh   = (const float*)d_in[14];
  const float* dbih   = (const float*)d_in[15];
  const float* dbhh   = (const float*)d_in[16];
  const float* Wout   = (const float*)d_in[17];
  const float* bout   = (const float*)d_in[18];
  float* out = (float*)d_out;

  float* ws = (float*)d_ws;
  float* xg_f   = ws + 0;          // 4194304
  float* xg_b   = ws + 4194304;    // 4194304
  float* outbuf = ws + 8388608;    // 2097152
  float* projo  = ws + 10485760;   // 2097152
  float* basep  = ws + 12582912;   // 8388608
  float* tagp   = ws + 20971520;   // 8388608
  // --- zeroed state block ---
  float* hT     = ws + 29360128;   // 65536  [2][1024][32]
  float* ctxT   = ws + 29425664;   // 65536  [2][1024][32]
  float* hrow   = ws + 29491200;   // 32768
  float* hencT  = ws + 29523968;   // 65536  [2][2][512][32]
  unsigned long long* argslot = (unsigned long long*)(ws + 29589504);  // 96 u64 (192 fl)
  unsigned* dslots = (unsigned*)(ws + 29589696);   // 129*256 = 33024 u32
  unsigned* dflags = (unsigned*)(ws + 29622720);   // 129*16  = 2064 u32
  unsigned* eslots = (unsigned*)(ws + 29624784);   // 128*128 = 16384 u32
  unsigned* eflags = (unsigned*)(ws + 29641168);   // 128*16  = 2048 u32
  // end: 29643216 floats

  // allow 160000 B dynamic LDS for the decoder
  (void)hipFuncSetAttribute((const void*)decoder_persistent,
                            hipFuncAttributeMaxDynamicSharedMemorySize, 160000);

  // zero all persistent-kernel state every call (graph-replay deterministic)
  hipMemsetAsync((void*)(ws + 29360128), 0, (size_t)(29643216 - 29360128) * sizeof(float), stream);

  // xg = emb @ Wih^T + bih + bhh   (M=2048, N=2048, K=512)
  gemm_nt<<<dim3(32, 16), 256, 0, stream>>>(emb, 512, Wih_f, 512, xg_f, 2048, bih_f, bhh_f, 512);
  gemm_nt<<<dim3(32, 16), 256, 0, stream>>>(emb, 512, Wih_b, 512, xg_b, 2048, bih_b, bhh_b, 512);
  // tagp = tag_embed @ dec_Wih[:, :512]^T   (M=2048, N=4096, K=512)
  gemm_nt<<<dim3(64, 16), 256, 0, stream>>>(tagemb, 512, dWih, DEC_IN, tagp, G4, nullptr, nullptr, 512);
  // encoder scan (persistent, register-resident Whh)
  encoder_persistent<<<256, 256, 0, stream>>>(xg_f, xg_b, Whh_f, Whh_b, mask, hencT, outbuf, eslots, eflags);
  // projo[bt,d] = sum_e attn_W[d,e]*output[bt,e]   (M=2048, N=1024, K=1024)
  gemm_nt<<<dim3(16, 16), 256, 0, stream>>>(outbuf, H2, attnW, H2, projo, H2, nullptr, nullptr, H2);
  // basep = aligned @ dec_Wih[:,1536:]^T + dbih + dbhh   (M=2048, N=4096, K=1024)
  gemm_nt<<<dim3(64, 16), 256, 0, stream>>>(outbuf, H2, dWih + 1536, DEC_IN, basep, G4, dbih, dbhh, H2);
  // persistent decoder
  decoder_persistent<<<256, 256, 160000, stream>>>(basep, tagp, dWhh, dWih, Wout, bout,
                                                   projo, outbuf, mask, hT, ctxT, hrow,
                                                   argslot, dslots, dflags, out);
}